// Round 1
// baseline (1386.219 us; speedup 1.0000x reference)
//
#include <hip/hip_runtime.h>
#include <hip/hip_bf16.h>
#include <math.h>

typedef __bf16 bf_t;
typedef __attribute__((ext_vector_type(8))) __bf16 bf16x8;
typedef __attribute__((ext_vector_type(4))) float floatx4;

#define EMBED 1024
#define HEADS 16
#define HDIM 64
#define HIDDEN 4096
#define BB 2
#define SS 2048
#define MTOT (BB*SS)   /* 4096 rows */
#define LDT 40         /* LDS row stride (bf16 elems): 80B, 16B-aligned, 2-way-bank free */

__device__ inline floatx4 mfma16(bf16x8 a, bf16x8 b, floatx4 c){
  return __builtin_amdgcn_mfma_f32_16x16x32_bf16(a, b, c, 0, 0, 0);
}

// ---------------- elementwise fp32 -> bf16 ----------------
__launch_bounds__(256)
__global__ void cvt_f2b_kernel(const float* __restrict__ in, bf_t* __restrict__ out, int n4){
  int i = blockIdx.x*256 + threadIdx.x;
  if(i < n4){
    const float4 v = *(const float4*)(in + (size_t)i*4);
    bf_t* o = out + (size_t)i*4;
    o[0]=(bf_t)v.x; o[1]=(bf_t)v.y; o[2]=(bf_t)v.z; o[3]=(bf_t)v.w;
  }
}

// ---------------- transpose fp32[R,C] -> bf16[C,R], batched over z ----------------
__launch_bounds__(256)
__global__ void transpose_f2b(const float* __restrict__ in, bf_t* __restrict__ out, int R, int C){
  __shared__ bf_t tile[32][33];
  const int z = blockIdx.z;
  in  += (size_t)z*R*C;
  out += (size_t)z*R*C;
  const int c0 = blockIdx.x*32, r0 = blockIdx.y*32;
  const int tx = threadIdx.x & 31, ty = threadIdx.x >> 5;
  #pragma unroll
  for(int i=0;i<4;i++)
    tile[ty + i*8][tx] = (bf_t)in[(size_t)(r0+ty+i*8)*C + c0 + tx];
  __syncthreads();
  #pragma unroll
  for(int i=0;i<4;i++)
    out[(size_t)(c0+ty+i*8)*R + r0 + tx] = tile[tx][ty+i*8];
}

// ---------------- transpose bf16[R,C] -> bf16[C,R], batched over z (for v) ----------------
__launch_bounds__(256)
__global__ void transpose_b2b(const bf_t* __restrict__ in, bf_t* __restrict__ out, int R, int C){
  __shared__ bf_t tile[32][33];
  const int z = blockIdx.z;
  in  += (size_t)z*R*C;
  out += (size_t)z*R*C;
  const int c0 = blockIdx.x*32, r0 = blockIdx.y*32;
  const int tx = threadIdx.x & 31, ty = threadIdx.x >> 5;
  #pragma unroll
  for(int i=0;i<4;i++)
    tile[ty + i*8][tx] = in[(size_t)(r0+ty+i*8)*C + c0 + tx];
  __syncthreads();
  #pragma unroll
  for(int i=0;i<4;i++)
    out[(size_t)(c0+ty+i*8)*R + r0 + tx] = tile[tx][ty+i*8];
}

// ---------------- generic GEMM: C[M,N] = A[M,K](bf16) @ BT[N,K](bf16)^T ----------------
// mode 0: out bf16 = acc + bias
// mode 1: out f32  = acc + bias + resid[row*N+col]
// mode 2: out bf16 = gelu(acc + bias)
__launch_bounds__(256)
__global__ void gemm_kernel(const bf_t* __restrict__ A, const bf_t* __restrict__ BT,
                            const float* __restrict__ bias, const float* __restrict__ resid,
                            float* __restrict__ outF, bf_t* __restrict__ outB,
                            int M, int N, int K, int mode){
  __shared__ __attribute__((aligned(16))) bf_t ldsA[64*LDT];
  __shared__ __attribute__((aligned(16))) bf_t ldsB[64*LDT];
  const int m0 = blockIdx.y*64;
  const int n0 = blockIdx.x*64;
  const int t  = threadIdx.x;
  const int w  = t >> 6;
  const int lane = t & 63;
  const int ln = lane & 15;
  const int q4 = lane >> 4;
  const int srow = t >> 2;        // 0..63
  const int skc  = (t & 3) * 8;   // 0,8,16,24

  floatx4 acc[4] = {};

  const bf_t* Aptr = A + (size_t)(m0 + srow)*K + skc;
  const bf_t* Bptr = BT + (size_t)(n0 + srow)*K + skc;

  for(int k0 = 0; k0 < K; k0 += 32){
    const bf16x8 av = *(const bf16x8*)(Aptr + k0);
    const bf16x8 bv = *(const bf16x8*)(Bptr + k0);
    __syncthreads();
    *(bf16x8*)(&ldsA[srow*LDT + skc]) = av;
    *(bf16x8*)(&ldsB[srow*LDT + skc]) = bv;
    __syncthreads();
    const bf16x8 a = *(const bf16x8*)(&ldsA[(w*16 + ln)*LDT + q4*8]);
    #pragma unroll
    for(int j=0;j<4;j++){
      const bf16x8 b = *(const bf16x8*)(&ldsB[(j*16 + ln)*LDT + q4*8]);
      acc[j] = mfma16(a, b, acc[j]);
    }
  }
  #pragma unroll
  for(int j=0;j<4;j++){
    const int col = n0 + j*16 + ln;
    const float bsv = bias ? bias[col] : 0.f;
    #pragma unroll
    for(int r=0;r<4;r++){
      const int row = m0 + w*16 + q4*4 + r;
      float c = acc[j][r] + bsv;
      const size_t idx = (size_t)row*N + col;
      if(mode == 1){
        outF[idx] = c + resid[idx];
      } else if(mode == 2){
        const float g = 0.5f*c*(1.0f + erff(c*0.70710678118f));
        outB[idx] = (bf_t)g;
      } else {
        outB[idx] = (bf_t)c;
      }
    }
  }
}

// ---------------- energy: scores[b,h,q,k] = (q . k)/8, K-dim = 64 ----------------
__launch_bounds__(256)
__global__ void energy_kernel(const bf_t* __restrict__ q, const bf_t* __restrict__ k,
                              float* __restrict__ attn){
  const int bh = blockIdx.z;
  const int b = bh >> 4, h = bh & 15;
  const int q0 = blockIdx.y * 64;
  const int c0 = blockIdx.x * 128;
  const int t = threadIdx.x;
  const int w = t >> 6;
  const int lane = t & 63;
  const int ln = lane & 15, q4 = lane >> 4;

  floatx4 acc[8] = {};

  const size_t qbase = ((size_t)(b*SS + q0 + w*16 + ln))*EMBED + h*HDIM + q4*8;
  const bf16x8 a0 = *(const bf16x8*)(q + qbase);
  const bf16x8 a1 = *(const bf16x8*)(q + qbase + 32);
  #pragma unroll
  for(int j=0;j<8;j++){
    const size_t kbase = ((size_t)(b*SS + c0 + j*16 + ln))*EMBED + h*HDIM + q4*8;
    const bf16x8 b0 = *(const bf16x8*)(k + kbase);
    const bf16x8 b1 = *(const bf16x8*)(k + kbase + 32);
    acc[j] = mfma16(a0, b0, acc[j]);
    acc[j] = mfma16(a1, b1, acc[j]);
  }
  float* out = attn + (size_t)bh*SS*SS;
  #pragma unroll
  for(int j=0;j<8;j++){
    const int col = c0 + j*16 + ln;
    #pragma unroll
    for(int r=0;r<4;r++){
      const int row = q0 + w*16 + q4*4 + r;
      out[(size_t)row*SS + col] = acc[j][r]*0.125f;
    }
  }
}

// ---------------- softmax over last dim (2048), in-place on fp32 ----------------
__launch_bounds__(256)
__global__ void softmax_kernel(float* __restrict__ attn){
  __shared__ float sred[4];
  float* p = attn + (size_t)blockIdx.x*SS;
  const int t = threadIdx.x;
  float4 v0 = *(float4*)(p + t*4);
  float4 v1 = *(float4*)(p + 1024 + t*4);
  float m = fmaxf(fmaxf(fmaxf(v0.x,v0.y),fmaxf(v0.z,v0.w)),
                  fmaxf(fmaxf(v1.x,v1.y),fmaxf(v1.z,v1.w)));
  #pragma unroll
  for(int o=32;o>0;o>>=1) m = fmaxf(m, __shfl_xor(m, o));
  if((t&63)==0) sred[t>>6] = m;
  __syncthreads();
  m = fmaxf(fmaxf(sred[0],sred[1]), fmaxf(sred[2],sred[3]));
  __syncthreads();
  v0.x = expf(v0.x-m); v0.y = expf(v0.y-m); v0.z = expf(v0.z-m); v0.w = expf(v0.w-m);
  v1.x = expf(v1.x-m); v1.y = expf(v1.y-m); v1.z = expf(v1.z-m); v1.w = expf(v1.w-m);
  float s = v0.x+v0.y+v0.z+v0.w + v1.x+v1.y+v1.z+v1.w;
  #pragma unroll
  for(int o=32;o>0;o>>=1) s += __shfl_xor(s, o);
  if((t&63)==0) sred[t>>6] = s;
  __syncthreads();
  s = sred[0]+sred[1]+sred[2]+sred[3];
  const float inv = 1.0f/s;
  v0.x*=inv; v0.y*=inv; v0.z*=inv; v0.w*=inv;
  v1.x*=inv; v1.y*=inv; v1.z*=inv; v1.w*=inv;
  *(float4*)(p + t*4) = v0;
  *(float4*)(p + 1024 + t*4) = v1;
}

// ---------------- PV: out[b,q,h,d] = sum_k attn[b,h,q,k] * vT[b,h,d,k] ----------------
__launch_bounds__(256)
__global__ void pv_kernel(const float* __restrict__ attn, const bf_t* __restrict__ vT,
                          bf_t* __restrict__ attn_out){
  __shared__ __attribute__((aligned(16))) bf_t ldsA[64*LDT];
  const int bh = blockIdx.y;
  const int b = bh >> 4, h = bh & 15;
  const int q0 = blockIdx.x * 64;
  const int t = threadIdx.x;
  const int w = t>>6, lane=t&63, ln=lane&15, q4=lane>>4;
  const int srow=t>>2, skc=(t&3)*8;
  floatx4 acc[4] = {};
  const float* Abase = attn + ((size_t)bh*SS + q0 + srow)*SS + skc;
  const bf_t* Bbase = vT + (size_t)bh*HDIM*SS;
  for(int k0=0;k0<SS;k0+=32){
    const float4 f0 = *(const float4*)(Abase + k0);
    const float4 f1 = *(const float4*)(Abase + k0 + 4);
    __syncthreads();
    bf_t* d = &ldsA[srow*LDT + skc];
    d[0]=(bf_t)f0.x; d[1]=(bf_t)f0.y; d[2]=(bf_t)f0.z; d[3]=(bf_t)f0.w;
    d[4]=(bf_t)f1.x; d[5]=(bf_t)f1.y; d[6]=(bf_t)f1.z; d[7]=(bf_t)f1.w;
    __syncthreads();
    const bf16x8 a = *(const bf16x8*)(&ldsA[(w*16+ln)*LDT + q4*8]);
    #pragma unroll
    for(int j=0;j<4;j++){
      const bf16x8 bv = *(const bf16x8*)(Bbase + ((size_t)(j*16+ln))*SS + k0 + q4*8);
      acc[j] = mfma16(a, bv, acc[j]);
    }
  }
  #pragma unroll
  for(int j=0;j<4;j++){
    const int col = j*16+ln;
    #pragma unroll
    for(int r=0;r<4;r++){
      const int row = q0 + w*16 + q4*4 + r;
      attn_out[((size_t)(b*SS+row))*EMBED + h*HDIM + col] = (bf_t)acc[j][r];
    }
  }
}

// ---------------- layernorm over 1024, optional f32 + bf16 outputs ----------------
__launch_bounds__(256)
__global__ void ln_kernel(const float* __restrict__ in, const float* __restrict__ gamma,
                          const float* __restrict__ beta, float* __restrict__ outF,
                          bf_t* __restrict__ outB){
  __shared__ float sred[4];
  const size_t row = blockIdx.x;
  const float* p = in + row*EMBED;
  const int t = threadIdx.x;
  const float4 v = *(const float4*)(p + t*4);
  float s = v.x+v.y+v.z+v.w;
  #pragma unroll
  for(int o=32;o>0;o>>=1) s += __shfl_xor(s, o);
  if((t&63)==0) sred[t>>6]=s;
  __syncthreads();
  const float mu = (sred[0]+sred[1]+sred[2]+sred[3]) * (1.0f/EMBED);
  __syncthreads();
  const float dx=v.x-mu, dy=v.y-mu, dz=v.z-mu, dw=v.w-mu;
  float s2 = dx*dx+dy*dy+dz*dz+dw*dw;
  #pragma unroll
  for(int o=32;o>0;o>>=1) s2 += __shfl_xor(s2, o);
  if((t&63)==0) sred[t>>6]=s2;
  __syncthreads();
  const float var = (sred[0]+sred[1]+sred[2]+sred[3]) * (1.0f/EMBED);
  const float rstd = rsqrtf(var + 1e-5f);
  const float4 g = *(const float4*)(gamma + t*4);
  const float4 bt = *(const float4*)(beta + t*4);
  float4 o;
  o.x = dx*rstd*g.x + bt.x;
  o.y = dy*rstd*g.y + bt.y;
  o.z = dz*rstd*g.z + bt.z;
  o.w = dw*rstd*g.w + bt.w;
  if(outF) *(float4*)(outF + row*EMBED + t*4) = o;
  if(outB){
    bf_t* ob = outB + row*EMBED + t*4;
    ob[0]=(bf_t)o.x; ob[1]=(bf_t)o.y; ob[2]=(bf_t)o.z; ob[3]=(bf_t)o.w;
  }
}

extern "C" void kernel_launch(void* const* d_in, const int* in_sizes, int n_in,
                              void* d_out, int out_size, void* d_ws, size_t ws_size,
                              hipStream_t stream){
  const float* x  = (const float*)d_in[0];
  const float* Wq = (const float*)d_in[1];
  const float* bq = (const float*)d_in[2];
  const float* Wk = (const float*)d_in[3];
  const float* bk = (const float*)d_in[4];
  const float* Wv = (const float*)d_in[5];
  const float* bv = (const float*)d_in[6];
  const float* Wo = (const float*)d_in[7];
  const float* bo = (const float*)d_in[8];
  const float* W1 = (const float*)d_in[9];
  const float* b1 = (const float*)d_in[10];
  const float* W2 = (const float*)d_in[11];
  const float* b2 = (const float*)d_in[12];
  const float* gamma = (const float*)d_in[13];
  const float* beta  = (const float*)d_in[14];

  float* outp = (float*)d_out;                      // [4096,1024]
  float* attn = outp + (size_t)MTOT*EMBED;          // [32,2048,2048]

  char* ws = (char*)d_ws;
  size_t off = 0;
  auto alloc = [&](size_t bytes)->void*{
    void* p = ws + off; off += (bytes + 255) & ~(size_t)255; return p;
  };
  bf_t* xb  = (bf_t*)alloc((size_t)MTOT*EMBED*2);
  bf_t* WqT = (bf_t*)alloc((size_t)EMBED*EMBED*2);
  bf_t* WkT = (bf_t*)alloc((size_t)EMBED*EMBED*2);
  bf_t* WvT = (bf_t*)alloc((size_t)EMBED*EMBED*2);
  bf_t* WoT = (bf_t*)alloc((size_t)EMBED*EMBED*2);
  bf_t* W1T = (bf_t*)alloc((size_t)EMBED*HIDDEN*2);
  bf_t* W2T = (bf_t*)alloc((size_t)HIDDEN*EMBED*2);
  bf_t* qb  = (bf_t*)alloc((size_t)MTOT*EMBED*2);
  bf_t* kb  = (bf_t*)alloc((size_t)MTOT*EMBED*2);
  bf_t* vb  = (bf_t*)alloc((size_t)MTOT*EMBED*2);
  bf_t* vT  = (bf_t*)alloc((size_t)MTOT*EMBED*2);
  bf_t* ao  = (bf_t*)alloc((size_t)MTOT*EMBED*2);  // attn_out bf16
  float* y  = (float*)alloc((size_t)MTOT*EMBED*4); // pre-LN fp32 (reused)
  float* hf = (float*)alloc((size_t)MTOT*EMBED*4); // h fp32
  bf_t* hb  = (bf_t*)alloc((size_t)MTOT*EMBED*2);  // h bf16
  bf_t* g   = (bf_t*)alloc((size_t)MTOT*HIDDEN*2); // gelu out bf16
  (void)ws_size; (void)n_in; (void)in_sizes; (void)out_size;

  // 1) convert x -> bf16
  cvt_f2b_kernel<<<dim3((MTOT*EMBED/4 + 255)/256), 256, 0, stream>>>(x, xb, MTOT*EMBED/4);
  // 2) transpose+convert weights to [N,K] bf16
  transpose_f2b<<<dim3(EMBED/32, EMBED/32, 1), 256, 0, stream>>>(Wq, WqT, EMBED, EMBED);
  transpose_f2b<<<dim3(EMBED/32, EMBED/32, 1), 256, 0, stream>>>(Wk, WkT, EMBED, EMBED);
  transpose_f2b<<<dim3(EMBED/32, EMBED/32, 1), 256, 0, stream>>>(Wv, WvT, EMBED, EMBED);
  transpose_f2b<<<dim3(EMBED/32, EMBED/32, 1), 256, 0, stream>>>(Wo, WoT, EMBED, EMBED);
  transpose_f2b<<<dim3(HIDDEN/32, EMBED/32, 1), 256, 0, stream>>>(W1, W1T, EMBED, HIDDEN);
  transpose_f2b<<<dim3(EMBED/32, HIDDEN/32, 1), 256, 0, stream>>>(W2, W2T, HIDDEN, EMBED);
  // 3) QKV projections -> bf16
  gemm_kernel<<<dim3(EMBED/64, MTOT/64), 256, 0, stream>>>(xb, WqT, bq, nullptr, nullptr, qb, MTOT, EMBED, EMBED, 0);
  gemm_kernel<<<dim3(EMBED/64, MTOT/64), 256, 0, stream>>>(xb, WkT, bk, nullptr, nullptr, kb, MTOT, EMBED, EMBED, 0);
  gemm_kernel<<<dim3(EMBED/64, MTOT/64), 256, 0, stream>>>(xb, WvT, bv, nullptr, nullptr, vb, MTOT, EMBED, EMBED, 0);
  // 4) transpose v per batch: [2048,1024] -> [1024,2048]  (vT[b,h,d,s])
  transpose_b2b<<<dim3(EMBED/32, SS/32, BB), 256, 0, stream>>>(vb, vT, SS, EMBED);
  // 5) energy (scaled scores) -> d_out attn region
  energy_kernel<<<dim3(SS/128, SS/64, BB*HEADS), 256, 0, stream>>>(qb, kb, attn);
  // 6) softmax in-place
  softmax_kernel<<<dim3(BB*HEADS*SS), 256, 0, stream>>>(attn);
  // 7) PV -> attn_out bf16
  pv_kernel<<<dim3(SS/64, BB*HEADS), 256, 0, stream>>>(attn, vT, ao);
  // 8) O-proj + bias + residual(x) -> y fp32
  gemm_kernel<<<dim3(EMBED/64, MTOT/64), 256, 0, stream>>>(ao, WoT, bo, x, y, nullptr, MTOT, EMBED, EMBED, 1);
  // 9) LN1 -> hf (fp32) + hb (bf16)
  ln_kernel<<<dim3(MTOT), 256, 0, stream>>>(y, gamma, beta, hf, hb);
  // 10) MLP1 + gelu -> g bf16
  gemm_kernel<<<dim3(HIDDEN/64, MTOT/64), 256, 0, stream>>>(hb, W1T, b1, nullptr, nullptr, g, MTOT, HIDDEN, EMBED, 2);
  // 11) MLP2 + bias + residual(hf) -> y fp32 (reuse)
  gemm_kernel<<<dim3(EMBED/64, MTOT/64), 256, 0, stream>>>(g, W2T, b2, hf, y, nullptr, MTOT, EMBED, HIDDEN, 1);
  // 12) LN2 -> d_out
  ln_kernel<<<dim3(MTOT), 256, 0, stream>>>(y, gamma, beta, outp, nullptr);
}